// Round 1
// baseline (98.189 us; speedup 1.0000x reference)
//
#include <hip/hip_runtime.h>
#include <math.h>

#define BB 16
#define CC 3
#define HH 512
#define WW 512
#define KW 11
#define RAD 5
#define TS 32
#define RS (TS + KW - 1)   // 42

__global__ __launch_bounds__(256) void psnr_lcs_fused(
    const float* __restrict__ pred, const float* __restrict__ target,
    float* __restrict__ acc)
{
    __shared__ float s_dot[RS][RS];
    __shared__ float s_pp[RS][RS];
    __shared__ float s_tt[RS][RS];
    __shared__ float h_dot[RS][TS];
    __shared__ float h_pp[RS][TS];
    __shared__ float h_tt[RS][TS];
    __shared__ float red[8];

    const int tid = threadIdx.x;
    const int bx = blockIdx.x, by = blockIdx.y, b = blockIdx.z;
    const long base = (long)b * CC * HH * WW;
    const int HW = HH * WW;

    // ---- load halo region, fold channels into dot/pp/tt (zero padding) ----
    for (int idx = tid; idx < RS * RS; idx += 256) {
        const int rr = idx / RS, cc = idx % RS;
        const int gy = by * TS + rr - RAD;
        const int gx = bx * TS + cc - RAD;
        float dot = 0.f, pp = 0.f, tt = 0.f;
        if (gx >= 0 && gx < WW && gy >= 0 && gy < HH) {
            const long off = base + (long)gy * WW + gx;
            const float p0 = pred[off],          t0 = target[off];
            const float p1 = pred[off + HW],     t1 = target[off + HW];
            const float p2 = pred[off + 2 * HW], t2 = target[off + 2 * HW];
            dot = p0 * t0 + p1 * t1 + p2 * t2;
            pp  = p0 * p0 + p1 * p1 + p2 * p2;
            tt  = t0 * t0 + t1 * t1 + t2 * t2;
        }
        s_dot[rr][cc] = dot;
        s_pp[rr][cc]  = pp;
        s_tt[rr][cc]  = tt;
    }
    __syncthreads();

    // ---- horizontal 11-sum: 42 rows x 32 cols ----
    for (int idx = tid; idx < RS * TS; idx += 256) {
        const int r = idx / TS, c = idx % TS;
        float sd = 0.f, sp = 0.f, st = 0.f;
        #pragma unroll
        for (int dx = 0; dx < KW; ++dx) {
            sd += s_dot[r][c + dx];
            sp += s_pp[r][c + dx];
            st += s_tt[r][c + dx];
        }
        h_dot[r][c] = sd;
        h_pp[r][c]  = sp;
        h_tt[r][c]  = st;
    }
    __syncthreads();

    // ---- vertical 11-sum + cosine + PSNR squared-error ----
    float cos_part = 0.f, sq_part = 0.f;
    const int oc = tid & 31;
    const int r0 = tid >> 5;
    #pragma unroll
    for (int k = 0; k < 4; ++k) {
        const int orow = r0 + k * 8;
        float sxy = 0.f, sxx = 0.f, syy = 0.f;
        #pragma unroll
        for (int dy = 0; dy < KW; ++dy) {
            sxy += h_dot[orow + dy][oc];
            sxx += h_pp[orow + dy][oc];
            syy += h_tt[orow + dy][oc];
        }
        cos_part += sxy / (sqrtf(sxx) * sqrtf(syy) + 1e-6f);
        // sum_c (p-t)^2 = pp - 2*dot + tt at the interior pixel
        const float pp  = s_pp[orow + RAD][oc + RAD];
        const float dt  = s_dot[orow + RAD][oc + RAD];
        const float tt2 = s_tt[orow + RAD][oc + RAD];
        sq_part += pp - 2.f * dt + tt2;
    }

    // ---- block reduce (wave shuffle then LDS across 4 waves) ----
    #pragma unroll
    for (int o = 32; o > 0; o >>= 1) {
        cos_part += __shfl_down(cos_part, o);
        sq_part  += __shfl_down(sq_part, o);
    }
    const int wave = tid >> 6, lane = tid & 63;
    if (lane == 0) { red[wave] = cos_part; red[wave + 4] = sq_part; }
    __syncthreads();
    if (tid == 0) {
        const float cs = red[0] + red[1] + red[2] + red[3];
        const float ss = red[4] + red[5] + red[6] + red[7];
        atomicAdd(&acc[b], ss);       // per-batch sum of squared error
        atomicAdd(&acc[BB], cs);      // global sum of cos
    }
}

__global__ void psnr_lcs_finalize(const float* __restrict__ acc,
                                  float* __restrict__ out)
{
    if (threadIdx.x == 0) {
        const float scale = 4.342944819032518f;   // 10 / ln(10)
        float s = 0.f;
        for (int b = 0; b < BB; ++b)
            s += logf(acc[b] / (float)(CC * HH * WW) + 1e-8f);
        const float psnr = scale * (s / (float)BB);
        const float lcs  = 1.f - acc[BB] / (float)(BB * HH * WW);
        out[0] = psnr + lcs;
    }
}

extern "C" void kernel_launch(void* const* d_in, const int* in_sizes, int n_in,
                              void* d_out, int out_size, void* d_ws, size_t ws_size,
                              hipStream_t stream)
{
    const float* pred   = (const float*)d_in[0];
    const float* target = (const float*)d_in[1];
    float* acc = (float*)d_ws;

    hipMemsetAsync(acc, 0, (BB + 1) * sizeof(float), stream);

    dim3 grid(WW / TS, HH / TS, BB);   // 16 x 16 x 16 = 4096 blocks
    psnr_lcs_fused<<<grid, 256, 0, stream>>>(pred, target, acc);
    psnr_lcs_finalize<<<1, 64, 0, stream>>>(acc, (float*)d_out);
}